// Round 6
// baseline (356.401 us; speedup 1.0000x reference)
//
#include <hip/hip_runtime.h>
#include <stdint.h>

#define K_DIM 1024
#define B_SZ 4
#define N_SEQ 2048
#define HEADS 16
#define DH 64
#define M_TOT (B_SZ * N_SEQ)  // 8192

typedef __bf16 bf16x8 __attribute__((ext_vector_type(8)));
typedef __bf16 bf16x4 __attribute__((ext_vector_type(4)));
typedef __bf16 bf16x2 __attribute__((ext_vector_type(2)));
typedef float f32x4 __attribute__((ext_vector_type(4)));
typedef float f32x16 __attribute__((ext_vector_type(16)));

typedef const uint32_t __attribute__((address_space(1))) gas_u32;
typedef uint32_t __attribute__((address_space(3))) las_u32;

#define CE_SCALE 0.1803368801f  // 0.125 * log2(e), folded into Q projection

__device__ __forceinline__ uint16_t f2bf(float f) {
  uint32_t u = __float_as_uint(f);
  u += 0x7FFFu + ((u >> 16) & 1u);  // round-nearest-even
  return (uint16_t)(u >> 16);
}

__device__ __forceinline__ void gld_lds16(const uint16_t* g, uint16_t* lds) {
  __builtin_amdgcn_global_load_lds((gas_u32*)g, (las_u32*)lds, 16, 0, 0);
}

// pack two f32 -> one u32 of 2x bf16 (compiler emits v_cvt_pk_bf16_f32)
__device__ __forceinline__ uint32_t pkbf(float a, float b) {
  bf16x2 t;
  t[0] = (__bf16)a;
  t[1] = (__bf16)b;
  return __builtin_bit_cast(uint32_t, t);
}

// v_permlane32_swap_b32: a' = [a.lo | b.lo], b' = [a.hi | b.hi]
__device__ __forceinline__ void pswap(uint32_t& a, uint32_t& b) {
  asm("v_permlane32_swap_b32 %0, %1" : "+v"(a), "+v"(b));
}

// ------------- transpose + convert weights (batched over 4) ----------------------
__global__ __launch_bounds__(256) void transpose_conv(const float* __restrict__ s0,
                                                      const float* __restrict__ s1,
                                                      const float* __restrict__ s2,
                                                      const float* __restrict__ s3,
                                                      uint16_t* __restrict__ dstbase) {
  __shared__ float tile[32][33];
  const int z = blockIdx.z;
  const float* src = (z == 0) ? s0 : (z == 1) ? s1 : (z == 2) ? s2 : s3;
  uint16_t* dst = dstbase + (size_t)z * 1024 * 1024;
  const int tx = threadIdx.x, ty = threadIdx.y;
  const int bx = blockIdx.x * 32, by = blockIdx.y * 32;
#pragma unroll
  for (int i = 0; i < 32; i += 8)
    tile[ty + i][tx] = src[(size_t)(by + ty + i) * 1024 + bx + tx];
  __syncthreads();
#pragma unroll
  for (int i = 0; i < 32; i += 8)
    dst[(size_t)(bx + ty + i) * 1024 + by + tx] = f2bf(tile[tx][ty + i]);
}

// ---------------- fused convert + QKV GEMM ----------------
// C[M,1024] = cvt_bf16(A_f32[M,1024]) @ B[1024,1024], BT[n][k] given.
// Replaces the former standalone fp32->bf16 conv kernel (saves ~150MB HBM
// round-trip + one dispatch): A is reg-staged from fp32 (T14: issue float4
// loads for kt+1 early, cvt_pk + swizzled ds_write after compute), B stays
// global_load_lds with pre-swizzled source. 2-phase double-buffer, one
// barrier per K-step. LDS chunk-XOR swizzle on both tiles (0 conflicts, r4).
// z=0 Q scaled -> [B,H,N,Dh]; z=1 K -> [B,H,N,Dh]; z=2 V -> [B,H,Dh,N].
__global__ __launch_bounds__(256, 2) void gemm_qkv_f32(const float* __restrict__ Aq,
                                                       const float* __restrict__ Ak,
                                                       const float* __restrict__ Av,
                                                       const uint16_t* __restrict__ BT,
                                                       uint16_t* __restrict__ Cout) {
  __shared__ __align__(16) uint16_t As[2][128 * 32];
  __shared__ __align__(16) uint16_t Bs[2][128 * 32];
  const int tid = threadIdx.x;
  const int wave = tid >> 6, lane = tid & 63;
  const int g = lane >> 4, c16 = lane & 15;

  // swizzled block mapping (XCD-local m-tiles, n fastest, z slowest)
  const int bid = blockIdx.x;
  const int xcd = bid & 7;
  const int l = bid >> 3;
  const int z = l >> 6;
  const int r = l & 63;
  const int n0 = (r & 7) * 128;
  const int m0 = (xcd * 8 + (r >> 3)) * 128;

  const int wr = wave >> 1, wc = wave & 1;
  const float scale = (z == 0) ? CE_SCALE : 1.f;
  const float* A = (z == 0) ? Aq : (z == 1) ? Ak : Av;
  BT += (size_t)z * 1024 * 1024;

  const f32x4 fzero = {0.f, 0.f, 0.f, 0.f};
  f32x4 acc[4][4];
#pragma unroll
  for (int i = 0; i < 4; ++i)
#pragma unroll
    for (int j = 0; j < 4; ++j) acc[i][j] = fzero;

  const int srow = wave * 32 + (lane >> 2);
  const int ch4 = lane & 3;
  // A fp32 source: UNswizzled column; swizzle applied on the LDS write addr.
  const float* ag0 = A + (size_t)(m0 + srow) * K_DIM + ch4 * 8;
  const float* ag1 = ag0 + (size_t)16 * K_DIM;
  // A LDS write offsets (chunk-XOR swizzled; key == ((srow+16)>>1)&3 too)
  const int akey = (srow >> 1) & 3;
  const int adst0 = srow * 32 + ((ch4 ^ akey) << 3);
  const int adst1 = (srow + 16) * 32 + ((ch4 ^ akey) << 3);
  // B bf16 source: PRE-swizzled column (global_load_lds writes linearly)
  const int scol = ((ch4 ^ akey) * 8);
  const uint16_t* bg0 = BT + (size_t)(n0 + srow) * K_DIM + scol;
  const uint16_t* bg1 = bg0 + (size_t)16 * K_DIM;
  const int lofb0 = (wave * 32) * 32;
  const int lofb1 = (wave * 32 + 16) * 32;

  // read-side swizzle key: rows read are wr*64 + i*16 + c16 -> ((row>>1)&3)
  // == ((c16>>1)&3) for all i, wr.
  const int rk = (c16 >> 1) & 3;

  // prologue: stage kt=0 into buffer 0
  float4 a0a = *(const float4*)(ag0);
  float4 a0b = *(const float4*)(ag0 + 4);
  float4 a1a = *(const float4*)(ag1);
  float4 a1b = *(const float4*)(ag1 + 4);
  gld_lds16(bg0, &Bs[0][lofb0]);
  gld_lds16(bg1, &Bs[0][lofb1]);
  {
    uint4 w0, w1;
    w0.x = pkbf(a0a.x, a0a.y); w0.y = pkbf(a0a.z, a0a.w);
    w0.z = pkbf(a0b.x, a0b.y); w0.w = pkbf(a0b.z, a0b.w);
    w1.x = pkbf(a1a.x, a1a.y); w1.y = pkbf(a1a.z, a1a.w);
    w1.z = pkbf(a1b.x, a1b.y); w1.w = pkbf(a1b.z, a1b.w);
    *(uint4*)&As[0][adst0] = w0;
    *(uint4*)&As[0][adst1] = w1;
  }
  __syncthreads();

  int cur = 0;
  for (int kt = 0; kt < K_DIM / 32; ++kt) {
    const int nxt = cur ^ 1;
    // phase A: issue next tile's loads (B direct-to-LDS, A to regs) -- they
    // stay in flight across the compute phase below.
    if (kt + 1 < K_DIM / 32) {
      a0a = *(const float4*)(ag0 + (kt + 1) * 32);
      a0b = *(const float4*)(ag0 + (kt + 1) * 32 + 4);
      a1a = *(const float4*)(ag1 + (kt + 1) * 32);
      a1b = *(const float4*)(ag1 + (kt + 1) * 32 + 4);
      gld_lds16(bg0 + (kt + 1) * 32, &Bs[nxt][lofb0]);
      gld_lds16(bg1 + (kt + 1) * 32, &Bs[nxt][lofb1]);
    }
    // phase B: compute current buffer
    bf16x8 avec[4], bvec[4];
#pragma unroll
    for (int i = 0; i < 4; ++i)
      avec[i] = *(const bf16x8*)&As[cur][(wr * 64 + i * 16 + c16) * 32 + ((g ^ rk) << 3)];
#pragma unroll
    for (int j = 0; j < 4; ++j)
      bvec[j] = *(const bf16x8*)&Bs[cur][(wc * 64 + j * 16 + c16) * 32 + ((g ^ rk) << 3)];
#pragma unroll
    for (int i = 0; i < 4; ++i)
#pragma unroll
      for (int j = 0; j < 4; ++j)
        acc[i][j] = __builtin_amdgcn_mfma_f32_16x16x32_bf16(avec[i], bvec[j], acc[i][j], 0, 0, 0);
    // phase C: convert + write A(kt+1) into the other buffer (its previous
    // readers finished at the end-of-iteration barrier of kt-1).
    if (kt + 1 < K_DIM / 32) {
      uint4 w0, w1;
      w0.x = pkbf(a0a.x, a0a.y); w0.y = pkbf(a0a.z, a0a.w);
      w0.z = pkbf(a0b.x, a0b.y); w0.w = pkbf(a0b.z, a0b.w);
      w1.x = pkbf(a1a.x, a1a.y); w1.y = pkbf(a1a.z, a1a.w);
      w1.z = pkbf(a1b.x, a1b.y); w1.w = pkbf(a1b.z, a1b.w);
      *(uint4*)&As[nxt][adst0] = w0;
      *(uint4*)&As[nxt][adst1] = w1;
    }
    // one barrier per K-step: drains gld_lds + ds_writes, releases buf[cur].
    __syncthreads();
    cur = nxt;
  }

#pragma unroll
  for (int i = 0; i < 4; ++i) {
#pragma unroll
    for (int j = 0; j < 4; ++j) {
      const int col = n0 + wc * 64 + j * 16 + c16;
      if (z == 2) {
        const int h = col >> 6, d = col & 63;
        const int row0 = m0 + wr * 64 + i * 16 + g * 4;
        const int b = row0 >> 11, n = row0 & 2047;
        ushort4 o;
        o.x = f2bf(acc[i][j][0]); o.y = f2bf(acc[i][j][1]);
        o.z = f2bf(acc[i][j][2]); o.w = f2bf(acc[i][j][3]);
        *(ushort4*)&Cout[(size_t)2 * M_TOT * 1024 +
                         (((size_t)(b * HEADS + h)) * DH + d) * N_SEQ + n] = o;
      } else {
#pragma unroll
        for (int r2 = 0; r2 < 4; ++r2) {
          const int row = m0 + wr * 64 + i * 16 + g * 4 + r2;
          const int b = row >> 11, n = row & 2047;
          const int h = col >> 6, d = col & 63;
          Cout[(size_t)z * M_TOT * 1024 + (((size_t)(b * HEADS + h)) * N_SEQ + n) * DH + d] =
              f2bf(acc[i][j][r2] * scale);
        }
      }
    }
  }
}

// ---------------- GEMM (output projection): fp32 out + bias ----------------
// C[M,1024] = A_bf16[M,1024] @ B[1024,1024], BT[n][k] given. 2-phase dbuf,
// chunk-XOR swizzle (0 conflicts). Same structure as gemm_qkv_f32 but A is
// bf16 via global_load_lds with pre-swizzled source.
template <int MODE>
__global__ __launch_bounds__(256, 2) void gemm_bf16(const uint16_t* __restrict__ A,
                                                    const uint16_t* __restrict__ BT,
                                                    void* __restrict__ Cout,
                                                    const float* __restrict__ bias) {
  __shared__ __align__(16) uint16_t As[2][128 * 32];
  __shared__ __align__(16) uint16_t Bs[2][128 * 32];
  const int tid = threadIdx.x;
  const int wave = tid >> 6, lane = tid & 63;
  const int g = lane >> 4, c16 = lane & 15;

  const int bid = blockIdx.x;
  const int xcd = bid & 7;
  const int l = bid >> 3;
  const int r = l & 63;
  const int n0 = (r & 7) * 128;
  const int m0 = (xcd * 8 + (r >> 3)) * 128;

  const int wr = wave >> 1, wc = wave & 1;

  const f32x4 fzero = {0.f, 0.f, 0.f, 0.f};
  f32x4 acc[4][4];
#pragma unroll
  for (int i = 0; i < 4; ++i)
#pragma unroll
    for (int j = 0; j < 4; ++j) acc[i][j] = fzero;

  const int srow = wave * 32 + (lane >> 2);
  const int scol = (((lane & 3) ^ ((srow >> 1) & 3)) * 8);
  const uint16_t* ag0 = A + (size_t)(m0 + srow) * K_DIM + scol;
  const uint16_t* ag1 = A + (size_t)(m0 + srow + 16) * K_DIM + scol;
  const uint16_t* bg0 = BT + (size_t)(n0 + srow) * K_DIM + scol;
  const uint16_t* bg1 = BT + (size_t)(n0 + srow + 16) * K_DIM + scol;
  const int lofa0 = (wave * 32) * 32;
  const int lofa1 = (wave * 32 + 16) * 32;

  const int rk = (c16 >> 1) & 3;

  gld_lds16(ag0, &As[0][lofa0]);
  gld_lds16(ag1, &As[0][lofa1]);
  gld_lds16(bg0, &Bs[0][lofa0]);
  gld_lds16(bg1, &Bs[0][lofa1]);
  __syncthreads();

  int cur = 0;
  for (int kt = 0; kt < K_DIM / 32; ++kt) {
    if (kt + 1 < K_DIM / 32) {
      const int nxt = cur ^ 1;
      gld_lds16(ag0 + (kt + 1) * 32, &As[nxt][lofa0]);
      gld_lds16(ag1 + (kt + 1) * 32, &As[nxt][lofa1]);
      gld_lds16(bg0 + (kt + 1) * 32, &Bs[nxt][lofa0]);
      gld_lds16(bg1 + (kt + 1) * 32, &Bs[nxt][lofa1]);
    }
    bf16x8 avec[4], bvec[4];
#pragma unroll
    for (int i = 0; i < 4; ++i)
      avec[i] = *(const bf16x8*)&As[cur][(wr * 64 + i * 16 + c16) * 32 + ((g ^ rk) << 3)];
#pragma unroll
    for (int j = 0; j < 4; ++j)
      bvec[j] = *(const bf16x8*)&Bs[cur][(wc * 64 + j * 16 + c16) * 32 + ((g ^ rk) << 3)];
#pragma unroll
    for (int i = 0; i < 4; ++i)
#pragma unroll
      for (int j = 0; j < 4; ++j)
        acc[i][j] = __builtin_amdgcn_mfma_f32_16x16x32_bf16(avec[i], bvec[j], acc[i][j], 0, 0, 0);
    __syncthreads();
    cur ^= 1;
  }

#pragma unroll
  for (int i = 0; i < 4; ++i) {
#pragma unroll
    for (int j = 0; j < 4; ++j) {
      const int col = n0 + wc * 64 + j * 16 + c16;
#pragma unroll
      for (int r2 = 0; r2 < 4; ++r2) {
        const int row = m0 + wr * 64 + i * 16 + g * 4 + r2;
        ((float*)Cout)[(size_t)row * 1024 + col] = acc[i][j][r2] + bias[col];
      }
    }
  }
}

// ---------------- flash attention v8 ----------------
// 256 threads (4 waves), 64 q/wave (2 sub-tiles of 32), 64-key tiles, double-
// buffered XOR-swizzled LDS, reg-staged prefetch.
// QK^T via mfma_f32_32x32x16_bf16 (A=K, B=Q): lane holds S^T[key=(r&3)+8(r>>2)+4hi]
// [query=lane&31]. exp2 in f32 regs, pack via cvt_pk_bf16 + v_permlane32_swap
// directly into the 32x32x16 A-fragment layout (k = hi*8+j) -> PV at full K=16
// per instr, 4096 FLOP/cy rate.
__global__ __launch_bounds__(256, 2) void attention_k(const uint16_t* __restrict__ qm,
                                                      const uint16_t* __restrict__ km,
                                                      const uint16_t* __restrict__ vtm,
                                                      uint16_t* __restrict__ om) {
  __shared__ __align__(16) uint16_t Ks[2 * 64 * 64];
  __shared__ __align__(16) uint16_t Vs[2 * 64 * 64];
  const int tid = threadIdx.x;
  const int wave = tid >> 6, lane = tid & 63;
  const int lrow = lane & 31;  // key_local (QK-A) / query (QK-B) / d_local (PV-B)
  const int hi = lane >> 5;

  const int bid = blockIdx.x;
  const int xcd = bid & 7;
  const int l0 = bid >> 3;
  const int bh = xcd * 8 + (l0 & 7);
  const int qblk = l0 >> 3;
  const int b = bh >> 4, h = bh & 15;
  const int q0w = qblk * 256 + wave * 64;

  const uint16_t* qbase = qm + (size_t)bh * N_SEQ * DH;
  const uint16_t* kbase = km + (size_t)bh * N_SEQ * DH;
  const uint16_t* vbase = vtm + (size_t)bh * DH * N_SEQ;

  // Q as 32x32x16 B-fragments: n = query = lrow, k(d) = step*16 + hi*8 + j
  bf16x8 qf[2][4];
#pragma unroll
  for (int qs = 0; qs < 2; ++qs) {
    const uint16_t* qp = qbase + (size_t)(q0w + qs * 32 + lrow) * DH + hi * 8;
#pragma unroll
    for (int step = 0; step < 4; ++step) qf[qs][step] = *(const bf16x8*)(qp + step * 16);
  }

  // loop-invariant swizzled LDS element offsets
  int koff[2][4];  // [ks][step]: K A-frag, row = ks*32+lrow, d = step*16+hi*8
  int voff[2][2][2];  // [ks][s][dt]: V B-frag, row(d) = dt*32+lrow, key = ks*32+s*16+hi*8
#pragma unroll
  for (int ks = 0; ks < 2; ++ks) {
    const int krow = ks * 32 + lrow;
#pragma unroll
    for (int step = 0; step < 4; ++step)
      koff[ks][step] = krow * 64 + ((((step << 1) | hi) ^ (krow & 7)) << 3);
#pragma unroll
    for (int s = 0; s < 2; ++s)
#pragma unroll
      for (int dt = 0; dt < 2; ++dt)
        voff[ks][s][dt] =
            (dt * 32 + lrow) * 64 + ((((ks << 2) | (s << 1) | hi) ^ (lrow & 7)) << 3);
  }

  f32x16 oacc[2][2];  // [qs][dt]: col = d_local = lrow, row(query) = (r&3)+8(r>>2)+4hi
#pragma unroll
  for (int qs = 0; qs < 2; ++qs)
#pragma unroll
    for (int dt = 0; dt < 2; ++dt)
#pragma unroll
      for (int i = 0; i < 16; ++i) oacc[qs][dt][i] = 0.f;
  float l[2] = {0.f, 0.f};

  // staging: 256 threads, 2 chunks each per tensor (row = key for K, d for V^T)
  const int ch = tid & 7;
  const int krow0 = tid >> 3, krow1 = 32 + (tid >> 3);
  const int kdst0 = krow0 * 64 + ((ch ^ (krow0 & 7)) << 3);
  const int kdst1 = krow1 * 64 + ((ch ^ (krow1 & 7)) << 3);

  uint4 kp0, kp1, vp0, vp1;
  kp0 = *(const uint4*)&kbase[(size_t)tid * 8];
  kp1 = *(const uint4*)&kbase[(size_t)(256 + tid) * 8];
  vp0 = *(const uint4*)&vbase[(size_t)krow0 * N_SEQ + ch * 8];
  vp1 = *(const uint4*)&vbase[(size_t)krow1 * N_SEQ + ch * 8];
  *(uint4*)&Ks[kdst0] = kp0;
  *(uint4*)&Ks[kdst1] = kp1;
  *(uint4*)&Vs[kdst0] = vp0;
  *(uint4*)&Vs[kdst1] = vp1;
  __syncthreads();

  for (int t = 0; t < N_SEQ / 64; ++t) {
    const int cur = t & 1;
    if (t < N_SEQ / 64 - 1) {
      const size_t ko = (size_t)(t + 1) * 4096;
      const int vc = (t + 1) * 64;
      kp0 = *(const uint4*)&kbase[ko + (size_t)tid * 8];
      kp1 = *(const uint4*)&kbase[ko + (size_t)(256 + tid) * 8];
      vp0 = *(const uint4*)&vbase[(size_t)krow0 * N_SEQ + vc + ch * 8];
      vp1 = *(const uint4*)&vbase[(size_t)krow1 * N_SEQ + vc + ch * 8];
    }
    const uint16_t* ksp = &Ks[cur * 4096];
    const uint16_t* vsp = &Vs[cur * 4096];

#pragma unroll
    for (int ks = 0; ks < 2; ++ks) {
      bf16x8 kf[4];
#pragma unroll
      for (int step = 0; step < 4; ++step) kf[step] = *(const bf16x8*)&ksp[koff[ks][step]];

      f32x16 z[2];
#pragma unroll
      for (int qs = 0; qs < 2; ++qs)
#pragma unroll
        for (int i = 0; i < 16; ++i) z[qs][i] = 0.f;

      __builtin_amdgcn_s_setprio(1);
#pragma unroll
      for (int step = 0; step < 4; ++step)
        z[0] = __builtin_amdgcn_mfma_f32_32x32x16_bf16(kf[step], qf[0][step], z[0], 0, 0, 0);
#pragma unroll
      for (int step = 0; step < 4; ++step)
        z[1] = __builtin_amdgcn_mfma_f32_32x32x16_bf16(kf[step], qf[1][step], z[1], 0, 0, 0);
      __builtin_amdgcn_s_setprio(0);

      // softmax piece + pack into PV A-fragments (keys hi*8+j per lane)
      uint32_t pa[2][2][4];  // [qs][s][word]
#pragma unroll
      for (int qs = 0; qs < 2; ++qs) {
        float p[16];
#pragma unroll
        for (int r = 0; r < 16; ++r) p[r] = __builtin_amdgcn_exp2f(z[qs][r]);
        l[qs] += (((p[0] + p[1]) + (p[2] + p[3])) + ((p[4] + p[5]) + (p[6] + p[7]))) +
                 (((p[8] + p[9]) + (p[10] + p[11])) + ((p[12] + p[13]) + (p[14] + p[15])));
#pragma unroll
        for (int s = 0; s < 2; ++s) {
          uint32_t w0 = pkbf(p[s * 8 + 0], p[s * 8 + 1]);
          uint32_t w1 = pkbf(p[s * 8 + 2], p[s * 8 + 3]);
          uint32_t w2 = pkbf(p[s * 8 + 4], p[s * 8 + 5]);
          uint32_t w3 = pkbf(p[s * 8 + 6], p[s * 8 + 7]);
          pswap(w0, w2);  // -> frag words 0 and 2
          pswap(w1, w3);  // -> frag words 1 and 3
          pa[qs][s][0] = w0; pa[qs][s][1] = w1; pa[qs][s][2] = w2; pa[qs][s][3] = w3;
        }
      }

      bf16x8 vf[2][2];
#pragma unroll
      for (int s = 0; s < 2; ++s)
#pragma unroll
        for (int dt = 0; dt < 2; ++dt) vf[s][dt] = *(const bf16x8*)&vsp[voff[ks][s][dt]];

      __builtin_amdgcn_s_setprio(1);
#pragma unroll
      for (int s = 0; s < 2; ++s)
#pragma unroll
        for (int qs = 0; qs < 2; ++qs) {
          uint4 u;
          u.x = pa[qs][s][0]; u.y = pa[qs][s][1]; u.z = pa[qs][s][2]; u.w = pa[qs][s][3];
          const bf16x8 paf = __builtin_bit_cast(bf16x8, u);
          oacc[qs][0] = __builtin_amdgcn_mfma_f32_32x32x16_bf16(paf, vf[s][0], oacc[qs][0], 0, 0, 0);
          oacc[qs][1] = __builtin_amdgcn_mfma_f32_32x32x16_bf16(paf, vf[s][1], oacc[qs][1], 0, 0, 0);
        }
      __builtin_amdgcn_s_setprio(0);
    }

    if (t < N_SEQ / 64 - 1) {
      // write NEXT tile into the other buffer; its previous readers finished
      // before the barrier at the end of iteration t-1.
      *(uint4*)&Ks[(cur ^ 1) * 4096 + kdst0] = kp0;
      *(uint4*)&Ks[(cur ^ 1) * 4096 + kdst1] = kp1;
      *(uint4*)&Vs[(cur ^ 1) * 4096 + kdst0] = vp0;
      *(uint4*)&Vs[(cur ^ 1) * 4096 + kdst1] = vp1;
      __syncthreads();
    }
  }

  // finalize denominators: lane's l is partial over its hi-half's key set
#pragma unroll
  for (int qs = 0; qs < 2; ++qs) l[qs] += __shfl_xor(l[qs], 32);

#pragma unroll
  for (int qs = 0; qs < 2; ++qs) {
#pragma unroll
    for (int r = 0; r < 16; ++r) {
      const int ql = (r & 3) + 8 * (r >> 2) + 4 * hi;  // query_local of this reg
      const float lr = __shfl(l[qs], ql);
      const float inv = 1.f / lr;
      const int row = q0w + qs * 32 + ql;
      const size_t base = ((size_t)b * N_SEQ + row) * 1024 + h * 64;
      om[base + lrow] = f2bf(oacc[qs][0][r] * inv);
      om[base + 32 + lrow] = f2bf(oacc[qs][1][r] * inv);
    }
  }
}

// ---------------- LayerNorm + residual ----------------
__global__ __launch_bounds__(256) void ln_res_k(const float* __restrict__ proj,
                                                const float* __restrict__ query,
                                                const float* __restrict__ gamma,
                                                const float* __restrict__ beta,
                                                float* __restrict__ out) {
  const int row = blockIdx.x;
  const int tid = threadIdx.x;
  const size_t base = (size_t)row * 1024 + tid * 4;
  float4 v = *(const float4*)(proj + base);
  float s = v.x + v.y + v.z + v.w;
  float s2 = v.x * v.x + v.y * v.y + v.z * v.z + v.w * v.w;
#pragma unroll
  for (int off = 1; off < 64; off <<= 1) {
    s += __shfl_xor(s, off);
    s2 += __shfl_xor(s2, off);
  }
  __shared__ float red[8];
  const int wave = tid >> 6, lane = tid & 63;
  if (lane == 0) { red[wave] = s; red[4 + wave] = s2; }
  __syncthreads();
  s = red[0] + red[1] + red[2] + red[3];
  s2 = red[4] + red[5] + red[6] + red[7];
  const float mu = s * (1.f / 1024.f);
  const float var = fmaxf(s2 * (1.f / 1024.f) - mu * mu, 0.f);
  const float rstd = rsqrtf(var + 1e-5f);
  float4 gq = *(const float4*)(gamma + tid * 4);
  float4 bq = *(const float4*)(beta + tid * 4);
  float4 qq = *(const float4*)(query + base);
  float4 o;
  o.x = (v.x - mu) * rstd * gq.x + bq.x + qq.x;
  o.y = (v.y - mu) * rstd * gq.y + bq.y + qq.y;
  o.z = (v.z - mu) * rstd * gq.z + bq.z + qq.z;
  o.w = (v.w - mu) * rstd * gq.w + bq.w + qq.w;
  *(float4*)(out + base) = o;
}

extern "C" void kernel_launch(void* const* d_in, const int* in_sizes, int n_in,
                              void* d_out, int out_size, void* d_ws, size_t ws_size,
                              hipStream_t stream) {
  (void)in_sizes; (void)n_in; (void)out_size; (void)ws_size;
  const float* query = (const float*)d_in[0];
  const float* key_ = (const float*)d_in[1];
  const float* value = (const float*)d_in[2];
  const float* Wq = (const float*)d_in[3];
  const float* Wk = (const float*)d_in[4];
  const float* Wv = (const float*)d_in[5];
  const float* Wo = (const float*)d_in[6];
  const float* bo = (const float*)d_in[7];
  const float* gamma = (const float*)d_in[8];
  const float* beta = (const float*)d_in[9];
  float* out = (float*)d_out;

  const size_t NELEM = (size_t)M_TOT * 1024;  // 8388608
  uint16_t* wsp = (uint16_t*)d_ws;
  uint16_t* WqT = wsp;                   // 4 x 1M bf16 (Wq,Wk,Wv,Wo contiguous)
  uint16_t* WoT = WqT + 3 * 1024 * 1024;
  uint16_t* xq = WqT + 4 * 1024 * 1024;  // region kept for attnO/proj aliasing
  uint16_t* qb = xq + 3 * NELEM;         // qb,kb,vt contiguous (z * NELEM)
  uint16_t* attnO = xq;                  // attention output (bf16)
  float* proj = (float*)(xq + NELEM);    // output-projection result (fp32, 32MB)

  transpose_conv<<<dim3(32, 32, 4), dim3(32, 8), 0, stream>>>(Wq, Wk, Wv, Wo, WqT);

  gemm_qkv_f32<<<1536, 256, 0, stream>>>(query, key_, value, WqT, qb);

  attention_k<<<512, 256, 0, stream>>>(qb, qb + NELEM, qb + 2 * NELEM, attnO);

  gemm_bf16<1><<<512, 256, 0, stream>>>(attnO, WoT, proj, bo);

  ln_res_k<<<8192, 256, 0, stream>>>(proj, query, gamma, beta, out);
}

// Round 7
// 337.509 us; speedup vs baseline: 1.0560x; 1.0560x over previous
//
#include <hip/hip_runtime.h>
#include <stdint.h>

#define K_DIM 1024
#define B_SZ 4
#define N_SEQ 2048
#define HEADS 16
#define DH 64
#define M_TOT (B_SZ * N_SEQ)  // 8192

typedef __bf16 bf16x8 __attribute__((ext_vector_type(8)));
typedef __bf16 bf16x4 __attribute__((ext_vector_type(4)));
typedef __bf16 bf16x2 __attribute__((ext_vector_type(2)));
typedef float f32x4 __attribute__((ext_vector_type(4)));
typedef float f32x16 __attribute__((ext_vector_type(16)));

typedef const uint32_t __attribute__((address_space(1))) gas_u32;
typedef uint32_t __attribute__((address_space(3))) las_u32;

#define CE_SCALE 0.1803368801f  // 0.125 * log2(e), folded into Q projection

__device__ __forceinline__ uint16_t f2bf(float f) {
  uint32_t u = __float_as_uint(f);
  u += 0x7FFFu + ((u >> 16) & 1u);  // round-nearest-even
  return (uint16_t)(u >> 16);
}

__device__ __forceinline__ void gld_lds16(const uint16_t* g, uint16_t* lds) {
  __builtin_amdgcn_global_load_lds((gas_u32*)g, (las_u32*)lds, 16, 0, 0);
}

// pack two f32 -> one u32 of 2x bf16 (compiler emits v_cvt_pk_bf16_f32)
__device__ __forceinline__ uint32_t pkbf(float a, float b) {
  bf16x2 t;
  t[0] = (__bf16)a;
  t[1] = (__bf16)b;
  return __builtin_bit_cast(uint32_t, t);
}

// v_permlane32_swap_b32: a' = [a.lo | b.lo], b' = [a.hi | b.hi]
__device__ __forceinline__ void pswap(uint32_t& a, uint32_t& b) {
  asm("v_permlane32_swap_b32 %0, %1" : "+v"(a), "+v"(b));
}

// ---------------- fused preprocessing: activations fp32->bf16 + weight
// transpose-convert, ONE dispatch (round-6 lesson: dispatch-count reduction
// must not touch inner loops; this merge changes nothing else).
// blocks [0, 24576): convert Q/K/V activations (z = bid>>13, 8192 blocks each)
// blocks [24576, 28672): transpose Wq/Wk/Wv/Wo 32x32 tiles (1024 blocks each)
__global__ __launch_bounds__(256) void prep_k(const float* __restrict__ aq,
                                              const float* __restrict__ ak,
                                              const float* __restrict__ av,
                                              const float* __restrict__ w0,
                                              const float* __restrict__ w1,
                                              const float* __restrict__ w2,
                                              const float* __restrict__ w3,
                                              uint16_t* __restrict__ xdst,
                                              uint16_t* __restrict__ wdst) {
  __shared__ float tile[32][33];
  const int bid = blockIdx.x;
  const int tid = threadIdx.x;
  if (bid < 3 * 8192) {
    const int z = bid >> 13;
    const int xb = bid & 8191;
    const float* src = (z == 0) ? aq : (z == 1) ? ak : av;
    uint16_t* dst = xdst + (size_t)z * M_TOT * K_DIM;
    const int i = xb * 256 + tid;  // < 2097152 == NELEM/4 exactly
    float4 v = ((const float4*)src)[i];
    ushort4 o;
    o.x = f2bf(v.x); o.y = f2bf(v.y); o.z = f2bf(v.z); o.w = f2bf(v.w);
    ((ushort4*)dst)[i] = o;
  } else {
    const int t = bid - 3 * 8192;  // 0..4095
    const int z = t >> 10;
    const int rb = t & 1023;
    const float* src = (z == 0) ? w0 : (z == 1) ? w1 : (z == 2) ? w2 : w3;
    uint16_t* dst = wdst + (size_t)z * 1024 * 1024;
    const int tx = tid & 31, ty = tid >> 5;  // 32 x 8
    const int bx = (rb & 31) * 32, by = (rb >> 5) * 32;
#pragma unroll
    for (int i = 0; i < 32; i += 8)
      tile[ty + i][tx] = src[(size_t)(by + ty + i) * 1024 + bx + tx];
    __syncthreads();
#pragma unroll
    for (int i = 0; i < 32; i += 8)
      dst[(size_t)(bx + ty + i) * 1024 + by + tx] = f2bf(tile[tx][ty + i]);
  }
}

// ---------------- GEMM: C[M,1024] = A[M,1024] @ B[1024,1024], BT[n][k] given -----
// XCD-locality swizzle: flat 1-D grid; XCD (bid&7) owns m-tiles [xcd*8, xcd*8+8),
// n fastest, z slowest -> per-XCD working set (A-slice 2MB + B 2MB) fits one L2.
// LDS chunk-XOR swizzle (T2): 0 conflicts (verified r4). 2-phase double-buffered
// staging: issue stage(kt+1 -> buf^1) first, compute(buf), ONE barrier/K-step
// (its implicit vmcnt(0) lands after compute has elapsed).
// MODE 3: fused QKV (z=0 Q scaled -> [B,H,N,Dh]; z=1 K -> [B,H,N,Dh]; z=2 V -> [B,H,Dh,N])
// MODE 1: fp32 out row-major + bias (output projection), z=0 only.
template <int MODE>
__global__ __launch_bounds__(256, 2) void gemm_bf16(const uint16_t* __restrict__ A,
                                                    const uint16_t* __restrict__ BT,
                                                    void* __restrict__ Cout,
                                                    const float* __restrict__ bias) {
  __shared__ __align__(16) uint16_t As[2][128 * 32];
  __shared__ __align__(16) uint16_t Bs[2][128 * 32];
  const int tid = threadIdx.x;
  const int wave = tid >> 6, lane = tid & 63;
  const int g = lane >> 4, c16 = lane & 15;

  // swizzled block mapping
  const int bid = blockIdx.x;
  const int xcd = bid & 7;
  const int l = bid >> 3;
  const int z = (MODE == 3) ? (l >> 6) : 0;
  const int r = l & 63;
  const int n0 = (r & 7) * 128;
  const int m0 = (xcd * 8 + (r >> 3)) * 128;

  const int wr = wave >> 1, wc = wave & 1;
  float scale = 1.f;
  if (MODE == 3) {
    A += (size_t)z * M_TOT * K_DIM;
    BT += (size_t)z * 1024 * 1024;
    scale = (z == 0) ? CE_SCALE : 1.f;
  }

  const f32x4 fzero = {0.f, 0.f, 0.f, 0.f};
  f32x4 acc[4][4];
#pragma unroll
  for (int i = 0; i < 4; ++i)
#pragma unroll
    for (int j = 0; j < 4; ++j) acc[i][j] = fzero;

  const int srow = wave * 32 + (lane >> 2);
  // pre-swizzled source column: LDS slot (srow, lane&3) receives global chunk
  // (lane&3) ^ ((srow>>1)&3). Same key for srow+16.
  const int scol = (((lane & 3) ^ ((srow >> 1) & 3)) * 8);
  const uint16_t* ag0 = A + (size_t)(m0 + srow) * K_DIM + scol;
  const uint16_t* ag1 = A + (size_t)(m0 + srow + 16) * K_DIM + scol;
  const uint16_t* bg0 = BT + (size_t)(n0 + srow) * K_DIM + scol;
  const uint16_t* bg1 = BT + (size_t)(n0 + srow + 16) * K_DIM + scol;
  const int lofa0 = (wave * 32) * 32;
  const int lofa1 = (wave * 32 + 16) * 32;

  // read-side swizzle key: rows read are wr*64 + i*16 + c16 -> ((row>>1)&3)
  // == ((c16>>1)&3) for all i, wr.
  const int rk = (c16 >> 1) & 3;

  // prologue: stage kt=0 into buffer 0
  gld_lds16(ag0, &As[0][lofa0]);
  gld_lds16(ag1, &As[0][lofa1]);
  gld_lds16(bg0, &Bs[0][lofa0]);
  gld_lds16(bg1, &Bs[0][lofa1]);
  __syncthreads();

  int cur = 0;
  for (int kt = 0; kt < K_DIM / 32; ++kt) {
    if (kt + 1 < K_DIM / 32) {
      const int nxt = cur ^ 1;
      gld_lds16(ag0 + (kt + 1) * 32, &As[nxt][lofa0]);
      gld_lds16(ag1 + (kt + 1) * 32, &As[nxt][lofa1]);
      gld_lds16(bg0 + (kt + 1) * 32, &Bs[nxt][lofa0]);
      gld_lds16(bg1 + (kt + 1) * 32, &Bs[nxt][lofa1]);
    }
    bf16x8 avec[4], bvec[4];
#pragma unroll
    for (int i = 0; i < 4; ++i)
      avec[i] = *(const bf16x8*)&As[cur][(wr * 64 + i * 16 + c16) * 32 + ((g ^ rk) << 3)];
#pragma unroll
    for (int j = 0; j < 4; ++j)
      bvec[j] = *(const bf16x8*)&Bs[cur][(wc * 64 + j * 16 + c16) * 32 + ((g ^ rk) << 3)];
#pragma unroll
    for (int i = 0; i < 4; ++i)
#pragma unroll
      for (int j = 0; j < 4; ++j)
        acc[i][j] = __builtin_amdgcn_mfma_f32_16x16x32_bf16(avec[i], bvec[j], acc[i][j], 0, 0, 0);
    __syncthreads();
    cur ^= 1;
  }

#pragma unroll
  for (int i = 0; i < 4; ++i) {
#pragma unroll
    for (int j = 0; j < 4; ++j) {
      const int col = n0 + wc * 64 + j * 16 + c16;
      if (MODE == 3 && z == 2) {
        const int h = col >> 6, d = col & 63;
        const int row0 = m0 + wr * 64 + i * 16 + g * 4;
        const int b = row0 >> 11, n = row0 & 2047;
        ushort4 o;
        o.x = f2bf(acc[i][j][0]); o.y = f2bf(acc[i][j][1]);
        o.z = f2bf(acc[i][j][2]); o.w = f2bf(acc[i][j][3]);
        *(ushort4*)&((uint16_t*)Cout)[(size_t)2 * M_TOT * 1024 +
                                      (((size_t)(b * HEADS + h)) * DH + d) * N_SEQ + n] = o;
      } else {
#pragma unroll
        for (int r2 = 0; r2 < 4; ++r2) {
          const int row = m0 + wr * 64 + i * 16 + g * 4 + r2;
          if (MODE == 3) {
            const int b = row >> 11, n = row & 2047;
            const int h = col >> 6, d = col & 63;
            ((uint16_t*)Cout)[(size_t)z * M_TOT * 1024 +
                              (((size_t)(b * HEADS + h)) * N_SEQ + n) * DH + d] =
                f2bf(acc[i][j][r2] * scale);
          } else {
            ((float*)Cout)[(size_t)row * 1024 + col] = acc[i][j][r2] + bias[col];
          }
        }
      }
    }
  }
}

// ---------------- flash attention v8 ----------------
// 256 threads (4 waves), 64 q/wave (2 sub-tiles of 32), 64-key tiles, double-
// buffered XOR-swizzled LDS, reg-staged prefetch.
// QK^T via mfma_f32_32x32x16_bf16 (A=K, B=Q): lane holds S^T[key=(r&3)+8(r>>2)+4hi]
// [query=lane&31]. exp2 in f32 regs, pack via cvt_pk_bf16 + v_permlane32_swap
// directly into the 32x32x16 A-fragment layout (k = hi*8+j) -> PV at full K=16
// per instr, 4096 FLOP/cy rate.
__global__ __launch_bounds__(256, 2) void attention_k(const uint16_t* __restrict__ qm,
                                                      const uint16_t* __restrict__ km,
                                                      const uint16_t* __restrict__ vtm,
                                                      uint16_t* __restrict__ om) {
  __shared__ __align__(16) uint16_t Ks[2 * 64 * 64];
  __shared__ __align__(16) uint16_t Vs[2 * 64 * 64];
  const int tid = threadIdx.x;
  const int wave = tid >> 6, lane = tid & 63;
  const int lrow = lane & 31;  // key_local (QK-A) / query (QK-B) / d_local (PV-B)
  const int hi = lane >> 5;

  const int bid = blockIdx.x;
  const int xcd = bid & 7;
  const int l0 = bid >> 3;
  const int bh = xcd * 8 + (l0 & 7);
  const int qblk = l0 >> 3;
  const int b = bh >> 4, h = bh & 15;
  const int q0w = qblk * 256 + wave * 64;

  const uint16_t* qbase = qm + (size_t)bh * N_SEQ * DH;
  const uint16_t* kbase = km + (size_t)bh * N_SEQ * DH;
  const uint16_t* vbase = vtm + (size_t)bh * DH * N_SEQ;

  // Q as 32x32x16 B-fragments: n = query = lrow, k(d) = step*16 + hi*8 + j
  bf16x8 qf[2][4];
#pragma unroll
  for (int qs = 0; qs < 2; ++qs) {
    const uint16_t* qp = qbase + (size_t)(q0w + qs * 32 + lrow) * DH + hi * 8;
#pragma unroll
    for (int step = 0; step < 4; ++step) qf[qs][step] = *(const bf16x8*)(qp + step * 16);
  }

  // loop-invariant swizzled LDS element offsets
  int koff[2][4];  // [ks][step]: K A-frag, row = ks*32+lrow, d = step*16+hi*8
  int voff[2][2][2];  // [ks][s][dt]: V B-frag, row(d) = dt*32+lrow, key = ks*32+s*16+hi*8
#pragma unroll
  for (int ks = 0; ks < 2; ++ks) {
    const int krow = ks * 32 + lrow;
#pragma unroll
    for (int step = 0; step < 4; ++step)
      koff[ks][step] = krow * 64 + ((((step << 1) | hi) ^ (krow & 7)) << 3);
#pragma unroll
    for (int s = 0; s < 2; ++s)
#pragma unroll
      for (int dt = 0; dt < 2; ++dt)
        voff[ks][s][dt] =
            (dt * 32 + lrow) * 64 + ((((ks << 2) | (s << 1) | hi) ^ (lrow & 7)) << 3);
  }

  f32x16 oacc[2][2];  // [qs][dt]: col = d_local = lrow, row(query) = (r&3)+8(r>>2)+4hi
#pragma unroll
  for (int qs = 0; qs < 2; ++qs)
#pragma unroll
    for (int dt = 0; dt < 2; ++dt)
#pragma unroll
      for (int i = 0; i < 16; ++i) oacc[qs][dt][i] = 0.f;
  float l[2] = {0.f, 0.f};

  // staging: 256 threads, 2 chunks each per tensor (row = key for K, d for V^T)
  const int ch = tid & 7;
  const int krow0 = tid >> 3, krow1 = 32 + (tid >> 3);
  const int kdst0 = krow0 * 64 + ((ch ^ (krow0 & 7)) << 3);
  const int kdst1 = krow1 * 64 + ((ch ^ (krow1 & 7)) << 3);

  uint4 kp0, kp1, vp0, vp1;
  kp0 = *(const uint4*)&kbase[(size_t)tid * 8];
  kp1 = *(const uint4*)&kbase[(size_t)(256 + tid) * 8];
  vp0 = *(const uint4*)&vbase[(size_t)krow0 * N_SEQ + ch * 8];
  vp1 = *(const uint4*)&vbase[(size_t)krow1 * N_SEQ + ch * 8];
  *(uint4*)&Ks[kdst0] = kp0;
  *(uint4*)&Ks[kdst1] = kp1;
  *(uint4*)&Vs[kdst0] = vp0;
  *(uint4*)&Vs[kdst1] = vp1;
  __syncthreads();

  for (int t = 0; t < N_SEQ / 64; ++t) {
    const int cur = t & 1;
    if (t < N_SEQ / 64 - 1) {
      const size_t ko = (size_t)(t + 1) * 4096;
      const int vc = (t + 1) * 64;
      kp0 = *(const uint4*)&kbase[ko + (size_t)tid * 8];
      kp1 = *(const uint4*)&kbase[ko + (size_t)(256 + tid) * 8];
      vp0 = *(const uint4*)&vbase[(size_t)krow0 * N_SEQ + vc + ch * 8];
      vp1 = *(const uint4*)&vbase[(size_t)krow1 * N_SEQ + vc + ch * 8];
    }
    const uint16_t* ksp = &Ks[cur * 4096];
    const uint16_t* vsp = &Vs[cur * 4096];

#pragma unroll
    for (int ks = 0; ks < 2; ++ks) {
      bf16x8 kf[4];
#pragma unroll
      for (int step = 0; step < 4; ++step) kf[step] = *(const bf16x8*)&ksp[koff[ks][step]];

      f32x16 z[2];
#pragma unroll
      for (int qs = 0; qs < 2; ++qs)
#pragma unroll
        for (int i = 0; i < 16; ++i) z[qs][i] = 0.f;

      __builtin_amdgcn_s_setprio(1);
#pragma unroll
      for (int step = 0; step < 4; ++step)
        z[0] = __builtin_amdgcn_mfma_f32_32x32x16_bf16(kf[step], qf[0][step], z[0], 0, 0, 0);
#pragma unroll
      for (int step = 0; step < 4; ++step)
        z[1] = __builtin_amdgcn_mfma_f32_32x32x16_bf16(kf[step], qf[1][step], z[1], 0, 0, 0);
      __builtin_amdgcn_s_setprio(0);

      // softmax piece + pack into PV A-fragments (keys hi*8+j per lane)
      uint32_t pa[2][2][4];  // [qs][s][word]
#pragma unroll
      for (int qs = 0; qs < 2; ++qs) {
        float p[16];
#pragma unroll
        for (int r = 0; r < 16; ++r) p[r] = __builtin_amdgcn_exp2f(z[qs][r]);
        l[qs] += (((p[0] + p[1]) + (p[2] + p[3])) + ((p[4] + p[5]) + (p[6] + p[7]))) +
                 (((p[8] + p[9]) + (p[10] + p[11])) + ((p[12] + p[13]) + (p[14] + p[15])));
#pragma unroll
        for (int s = 0; s < 2; ++s) {
          uint32_t w0 = pkbf(p[s * 8 + 0], p[s * 8 + 1]);
          uint32_t w1 = pkbf(p[s * 8 + 2], p[s * 8 + 3]);
          uint32_t w2 = pkbf(p[s * 8 + 4], p[s * 8 + 5]);
          uint32_t w3 = pkbf(p[s * 8 + 6], p[s * 8 + 7]);
          pswap(w0, w2);  // -> frag words 0 and 2
          pswap(w1, w3);  // -> frag words 1 and 3
          pa[qs][s][0] = w0; pa[qs][s][1] = w1; pa[qs][s][2] = w2; pa[qs][s][3] = w3;
        }
      }

      bf16x8 vf[2][2];
#pragma unroll
      for (int s = 0; s < 2; ++s)
#pragma unroll
        for (int dt = 0; dt < 2; ++dt) vf[s][dt] = *(const bf16x8*)&vsp[voff[ks][s][dt]];

      __builtin_amdgcn_s_setprio(1);
#pragma unroll
      for (int s = 0; s < 2; ++s)
#pragma unroll
        for (int qs = 0; qs < 2; ++qs) {
          uint4 u;
          u.x = pa[qs][s][0]; u.y = pa[qs][s][1]; u.z = pa[qs][s][2]; u.w = pa[qs][s][3];
          const bf16x8 paf = __builtin_bit_cast(bf16x8, u);
          oacc[qs][0] = __builtin_amdgcn_mfma_f32_32x32x16_bf16(paf, vf[s][0], oacc[qs][0], 0, 0, 0);
          oacc[qs][1] = __builtin_amdgcn_mfma_f32_32x32x16_bf16(paf, vf[s][1], oacc[qs][1], 0, 0, 0);
        }
      __builtin_amdgcn_s_setprio(0);
    }

    if (t < N_SEQ / 64 - 1) {
      // write NEXT tile into the other buffer; its previous readers finished
      // before the barrier at the end of iteration t-1.
      *(uint4*)&Ks[(cur ^ 1) * 4096 + kdst0] = kp0;
      *(uint4*)&Ks[(cur ^ 1) * 4096 + kdst1] = kp1;
      *(uint4*)&Vs[(cur ^ 1) * 4096 + kdst0] = vp0;
      *(uint4*)&Vs[(cur ^ 1) * 4096 + kdst1] = vp1;
      __syncthreads();
    }
  }

  // finalize denominators: lane's l is partial over its hi-half's key set
#pragma unroll
  for (int qs = 0; qs < 2; ++qs) l[qs] += __shfl_xor(l[qs], 32);

#pragma unroll
  for (int qs = 0; qs < 2; ++qs) {
#pragma unroll
    for (int r = 0; r < 16; ++r) {
      const int ql = (r & 3) + 8 * (r >> 2) + 4 * hi;  // query_local of this reg
      const float lr = __shfl(l[qs], ql);
      const float inv = 1.f / lr;
      const int row = q0w + qs * 32 + ql;
      const size_t base = ((size_t)b * N_SEQ + row) * 1024 + h * 64;
      om[base + lrow] = f2bf(oacc[qs][0][r] * inv);
      om[base + 32 + lrow] = f2bf(oacc[qs][1][r] * inv);
    }
  }
}

// ---------------- LayerNorm + residual ----------------
__global__ __launch_bounds__(256) void ln_res_k(const float* __restrict__ proj,
                                                const float* __restrict__ query,
                                                const float* __restrict__ gamma,
                                                const float* __restrict__ beta,
                                                float* __restrict__ out) {
  const int row = blockIdx.x;
  const int tid = threadIdx.x;
  const size_t base = (size_t)row * 1024 + tid * 4;
  float4 v = *(const float4*)(proj + base);
  float s = v.x + v.y + v.z + v.w;
  float s2 = v.x * v.x + v.y * v.y + v.z * v.z + v.w * v.w;
#pragma unroll
  for (int off = 1; off < 64; off <<= 1) {
    s += __shfl_xor(s, off);
    s2 += __shfl_xor(s2, off);
  }
  __shared__ float red[8];
  const int wave = tid >> 6, lane = tid & 63;
  if (lane == 0) { red[wave] = s; red[4 + wave] = s2; }
  __syncthreads();
  s = red[0] + red[1] + red[2] + red[3];
  s2 = red[4] + red[5] + red[6] + red[7];
  const float mu = s * (1.f / 1024.f);
  const float var = fmaxf(s2 * (1.f / 1024.f) - mu * mu, 0.f);
  const float rstd = rsqrtf(var + 1e-5f);
  float4 gq = *(const float4*)(gamma + tid * 4);
  float4 bq = *(const float4*)(beta + tid * 4);
  float4 qq = *(const float4*)(query + base);
  float4 o;
  o.x = (v.x - mu) * rstd * gq.x + bq.x + qq.x;
  o.y = (v.y - mu) * rstd * gq.y + bq.y + qq.y;
  o.z = (v.z - mu) * rstd * gq.z + bq.z + qq.z;
  o.w = (v.w - mu) * rstd * gq.w + bq.w + qq.w;
  *(float4*)(out + base) = o;
}

extern "C" void kernel_launch(void* const* d_in, const int* in_sizes, int n_in,
                              void* d_out, int out_size, void* d_ws, size_t ws_size,
                              hipStream_t stream) {
  (void)in_sizes; (void)n_in; (void)out_size; (void)ws_size;
  const float* query = (const float*)d_in[0];
  const float* key_ = (const float*)d_in[1];
  const float* value = (const float*)d_in[2];
  const float* Wq = (const float*)d_in[3];
  const float* Wk = (const float*)d_in[4];
  const float* Wv = (const float*)d_in[5];
  const float* Wo = (const float*)d_in[6];
  const float* bo = (const float*)d_in[7];
  const float* gamma = (const float*)d_in[8];
  const float* beta = (const float*)d_in[9];
  float* out = (float*)d_out;

  const size_t NELEM = (size_t)M_TOT * 1024;  // 8388608
  uint16_t* wsp = (uint16_t*)d_ws;
  uint16_t* WqT = wsp;                   // 4 x 1M bf16 (Wq,Wk,Wv,Wo contiguous)
  uint16_t* WoT = WqT + 3 * 1024 * 1024;
  uint16_t* xq = WqT + 4 * 1024 * 1024;  // xq,xk,xv contiguous (3 x NELEM)
  uint16_t* qb = xq + 3 * NELEM;         // qb,kb,vt contiguous (z * NELEM)
  uint16_t* attnO = xq;                  // alias: xq dead after QKV-GEMM
  float* proj = (float*)(xq + NELEM);    // alias: xk+xv dead after QKV-GEMM (32MB)

  // fused preprocessing: 24576 conv blocks + 4096 transpose blocks
  prep_k<<<28672, 256, 0, stream>>>(query, key_, value, Wq, Wk, Wv, Wo, xq, WqT);

  gemm_bf16<3><<<1536, 256, 0, stream>>>(xq, WqT, qb, nullptr);

  attention_k<<<512, 256, 0, stream>>>(qb, qb + NELEM, qb + 2 * NELEM, attnO);

  gemm_bf16<1><<<512, 256, 0, stream>>>(attnO, WoT, proj, bo);

  ln_res_k<<<8192, 256, 0, stream>>>(proj, query, gamma, beta, out);
}

// Round 8
// 337.412 us; speedup vs baseline: 1.0563x; 1.0003x over previous
//
#include <hip/hip_runtime.h>
#include <stdint.h>

#define K_DIM 1024
#define B_SZ 4
#define N_SEQ 2048
#define HEADS 16
#define DH 64
#define M_TOT (B_SZ * N_SEQ)  // 8192

typedef __bf16 bf16x8 __attribute__((ext_vector_type(8)));
typedef __bf16 bf16x4 __attribute__((ext_vector_type(4)));
typedef __bf16 bf16x2 __attribute__((ext_vector_type(2)));
typedef float f32x4 __attribute__((ext_vector_type(4)));
typedef float f32x16 __attribute__((ext_vector_type(16)));

typedef const uint32_t __attribute__((address_space(1))) gas_u32;
typedef uint32_t __attribute__((address_space(3))) las_u32;

#define CE_SCALE 0.1803368801f  // 0.125 * log2(e), folded into Q projection

__device__ __forceinline__ uint16_t f2bf(float f) {
  uint32_t u = __float_as_uint(f);
  u += 0x7FFFu + ((u >> 16) & 1u);  // round-nearest-even
  return (uint16_t)(u >> 16);
}

__device__ __forceinline__ void gld_lds16(const uint16_t* g, uint16_t* lds) {
  __builtin_amdgcn_global_load_lds((gas_u32*)g, (las_u32*)lds, 16, 0, 0);
}

// pack two f32 -> one u32 of 2x bf16 (compiler emits v_cvt_pk_bf16_f32)
__device__ __forceinline__ uint32_t pkbf(float a, float b) {
  bf16x2 t;
  t[0] = (__bf16)a;
  t[1] = (__bf16)b;
  return __builtin_bit_cast(uint32_t, t);
}

// v_permlane32_swap_b32: a' = [a.lo | b.lo], b' = [a.hi | b.hi]
__device__ __forceinline__ void pswap(uint32_t& a, uint32_t& b) {
  asm("v_permlane32_swap_b32 %0, %1" : "+v"(a), "+v"(b));
}

// ---------------- fused preprocessing: activations fp32->bf16 + weight
// transpose-convert, ONE dispatch.
// blocks [0, 24576): convert Q/K/V activations (z = bid>>13, 8192 blocks each)
// blocks [24576, 28672): transpose Wq/Wk/Wv/Wo 32x32 tiles (1024 blocks each)
__global__ __launch_bounds__(256) void prep_k(const float* __restrict__ aq,
                                              const float* __restrict__ ak,
                                              const float* __restrict__ av,
                                              const float* __restrict__ w0,
                                              const float* __restrict__ w1,
                                              const float* __restrict__ w2,
                                              const float* __restrict__ w3,
                                              uint16_t* __restrict__ xdst,
                                              uint16_t* __restrict__ wdst) {
  __shared__ float tile[32][33];
  const int bid = blockIdx.x;
  const int tid = threadIdx.x;
  if (bid < 3 * 8192) {
    const int z = bid >> 13;
    const int xb = bid & 8191;
    const float* src = (z == 0) ? aq : (z == 1) ? ak : av;
    uint16_t* dst = xdst + (size_t)z * M_TOT * K_DIM;
    const int i = xb * 256 + tid;  // < 2097152 == NELEM/4 exactly
    float4 v = ((const float4*)src)[i];
    ushort4 o;
    o.x = f2bf(v.x); o.y = f2bf(v.y); o.z = f2bf(v.z); o.w = f2bf(v.w);
    ((ushort4*)dst)[i] = o;
  } else {
    const int t = bid - 3 * 8192;  // 0..4095
    const int z = t >> 10;
    const int rb = t & 1023;
    const float* src = (z == 0) ? w0 : (z == 1) ? w1 : (z == 2) ? w2 : w3;
    uint16_t* dst = wdst + (size_t)z * 1024 * 1024;
    const int tx = tid & 31, ty = tid >> 5;  // 32 x 8
    const int bx = (rb & 31) * 32, by = (rb >> 5) * 32;
#pragma unroll
    for (int i = 0; i < 32; i += 8)
      tile[ty + i][tx] = src[(size_t)(by + ty + i) * 1024 + bx + tx];
    __syncthreads();
#pragma unroll
    for (int i = 0; i < 32; i += 8)
      dst[(size_t)(bx + ty + i) * 1024 + by + tx] = f2bf(tile[tx][ty + i]);
  }
}

// ---------------- GEMM: C[M,1024] = A[M,1024] @ B[1024,1024], BT[n][k] given -----
// v2 tile: BM=256, BN=128, BK=64, 512 threads (8 waves, 4x2), 96KB LDS dbuf.
// Rationale (r7 counters): 128^2/BK32 gave 16 MFMA x 8cy = 128 cy of matrix
// work per exposed global->LDS latency window -> MfmaUtil 24%, 644 TF. This
// tile: 32 MFMA/wave/K-step (256 cy) per window, 16 K-steps (half the
// barriers), SAME stage->compute->barrier sync structure (no new races).
// LDS chunk-XOR swizzle re-derived for 64-elem rows: LDS(row, c) holds global
// chunk c ^ (row&7); reads use chunk ((ksub*4+g) ^ (c16&7)) -> quarter-wave
// lanes cover all 8 bank groups, conflict-free (r4 method).
// Staging: 6 gld_lds calls/thread (A 4, B 2), each call = wave-uniform LDS
// base + lane*16B (linear), global source pre-swizzled per-lane.
// Grids: MODE 3 -> 768 blocks (z = bid>>8, 3/CU balanced); MODE 1 -> 256.
// XCD swizzle: xcd = bid&7 owns m-rows [xcd*1024, +1024) per z (A 2MB + B 2MB
// per XCD-L2).
// MODE 3: fused QKV (z=0 Q scaled -> [B,H,N,Dh]; z=1 K -> [B,H,N,Dh]; z=2 V -> [B,H,Dh,N])
// MODE 1: fp32 out row-major + bias (output projection), z=0 only.
template <int MODE>
__global__ __launch_bounds__(512, 2) void gemm_bf16(const uint16_t* __restrict__ A,
                                                    const uint16_t* __restrict__ BT,
                                                    void* __restrict__ Cout,
                                                    const float* __restrict__ bias) {
  __shared__ __align__(16) uint16_t As[2][256 * 64];  // 64KB
  __shared__ __align__(16) uint16_t Bs[2][128 * 64];  // 32KB
  const int tid = threadIdx.x;
  const int wave = tid >> 6, lane = tid & 63;
  const int g = lane >> 4, c16 = lane & 15;

  const int bid = blockIdx.x;
  const int z = (MODE == 3) ? (bid >> 8) : 0;
  const int r = bid & 255;
  const int xcd = r & 7;
  const int l = r >> 3;  // 0..31
  const int m0 = (xcd * 4 + (l >> 3)) * 256;
  const int n0 = (l & 7) * 128;

  const int wr = wave >> 1, wc = wave & 1;  // 4 x 2 wave grid, 64x64 per wave
  float scale = 1.f;
  if (MODE == 3) {
    A += (size_t)z * M_TOT * K_DIM;
    BT += (size_t)z * 1024 * 1024;
    scale = (z == 0) ? CE_SCALE : 1.f;
  }

  const f32x4 fzero = {0.f, 0.f, 0.f, 0.f};
  f32x4 acc[4][4];
#pragma unroll
  for (int i = 0; i < 4; ++i)
#pragma unroll
    for (int j = 0; j < 4; ++j) acc[i][j] = fzero;

  // staging geometry: one gld_lds call = one wave writes 1KB (64 x 16B linear).
  // A tile 32KB = 32 calls (4/wave); B tile 16KB = 16 calls (2/wave).
  const int lsub = lane >> 3;  // row within the call's 8-row group
  const int ch = lane & 7;     // 16B chunk within 128B row
  const uint16_t* agp[4];
  int aldo[4];
#pragma unroll
  for (int q = 0; q < 4; ++q) {
    const int rowA = (wave * 4 + q) * 8 + lsub;  // 0..255
    agp[q] = A + (size_t)(m0 + rowA) * K_DIM + ((ch ^ (rowA & 7)) * 8);
    aldo[q] = (wave * 4 + q) * 512;  // element offset; HW adds lane*8 elems
  }
  const uint16_t* bgp[2];
  int bldo[2];
#pragma unroll
  for (int q = 0; q < 2; ++q) {
    const int rowB = (wave * 2 + q) * 8 + lsub;  // 0..127
    bgp[q] = BT + (size_t)(n0 + rowB) * K_DIM + ((ch ^ (rowB & 7)) * 8);
    bldo[q] = (wave * 2 + q) * 512;
  }

  const int rk = c16 & 7;  // read-side swizzle key (row&7 == c16&7 for frag rows)

  // prologue: stage kt=0 into buffer 0
#pragma unroll
  for (int q = 0; q < 4; ++q) gld_lds16(agp[q], &As[0][aldo[q]]);
#pragma unroll
  for (int q = 0; q < 2; ++q) gld_lds16(bgp[q], &Bs[0][bldo[q]]);
  __syncthreads();

  int cur = 0;
  for (int kt = 0; kt < K_DIM / 64; ++kt) {
    // phase A: issue next K-tile's staging into the other buffer
    if (kt + 1 < K_DIM / 64) {
      const int nxt = cur ^ 1;
#pragma unroll
      for (int q = 0; q < 4; ++q) gld_lds16(agp[q] + (kt + 1) * 64, &As[nxt][aldo[q]]);
#pragma unroll
      for (int q = 0; q < 2; ++q) gld_lds16(bgp[q] + (kt + 1) * 64, &Bs[nxt][bldo[q]]);
    }
    // phase B: compute current buffer (2 ksub of K=32 -> 32 MFMA)
#pragma unroll
    for (int ksub = 0; ksub < 2; ++ksub) {
      const int co = (((ksub << 2) | g) ^ rk) << 3;
      bf16x8 avec[4], bvec[4];
#pragma unroll
      for (int i = 0; i < 4; ++i)
        avec[i] = *(const bf16x8*)&As[cur][(wr * 64 + i * 16 + c16) * 64 + co];
#pragma unroll
      for (int j = 0; j < 4; ++j)
        bvec[j] = *(const bf16x8*)&Bs[cur][(wc * 64 + j * 16 + c16) * 64 + co];
#pragma unroll
      for (int i = 0; i < 4; ++i)
#pragma unroll
        for (int j = 0; j < 4; ++j)
          acc[i][j] = __builtin_amdgcn_mfma_f32_16x16x32_bf16(avec[i], bvec[j], acc[i][j], 0, 0, 0);
    }
    // one barrier per K-step: implicit vmcnt(0) drains the prefetch AFTER
    // 256 cy of MFMA has elapsed; also releases buf[cur] for the next stage.
    __syncthreads();
    cur ^= 1;
  }

#pragma unroll
  for (int i = 0; i < 4; ++i) {
#pragma unroll
    for (int j = 0; j < 4; ++j) {
      const int col = n0 + wc * 64 + j * 16 + c16;
      if (MODE == 3 && z == 2) {
        const int h = col >> 6, d = col & 63;
        const int row0 = m0 + wr * 64 + i * 16 + g * 4;
        const int b = row0 >> 11, n = row0 & 2047;
        ushort4 o;
        o.x = f2bf(acc[i][j][0]); o.y = f2bf(acc[i][j][1]);
        o.z = f2bf(acc[i][j][2]); o.w = f2bf(acc[i][j][3]);
        *(ushort4*)&((uint16_t*)Cout)[(size_t)2 * M_TOT * 1024 +
                                      (((size_t)(b * HEADS + h)) * DH + d) * N_SEQ + n] = o;
      } else {
#pragma unroll
        for (int r2 = 0; r2 < 4; ++r2) {
          const int row = m0 + wr * 64 + i * 16 + g * 4 + r2;
          if (MODE == 3) {
            const int b = row >> 11, n = row & 2047;
            const int h = col >> 6, d = col & 63;
            ((uint16_t*)Cout)[(size_t)z * M_TOT * 1024 +
                              (((size_t)(b * HEADS + h)) * N_SEQ + n) * DH + d] =
                f2bf(acc[i][j][r2] * scale);
          } else {
            ((float*)Cout)[(size_t)row * 1024 + col] = acc[i][j][r2] + bias[col];
          }
        }
      }
    }
  }
}

// ---------------- flash attention v8 ----------------
// 256 threads (4 waves), 64 q/wave (2 sub-tiles of 32), 64-key tiles, double-
// buffered XOR-swizzled LDS, reg-staged prefetch.
// QK^T via mfma_f32_32x32x16_bf16 (A=K, B=Q): lane holds S^T[key=(r&3)+8(r>>2)+4hi]
// [query=lane&31]. exp2 in f32 regs, pack via cvt_pk_bf16 + v_permlane32_swap
// directly into the 32x32x16 A-fragment layout (k = hi*8+j) -> PV at full K=16
// per instr, 4096 FLOP/cy rate.
__global__ __launch_bounds__(256, 2) void attention_k(const uint16_t* __restrict__ qm,
                                                      const uint16_t* __restrict__ km,
                                                      const uint16_t* __restrict__ vtm,
                                                      uint16_t* __restrict__ om) {
  __shared__ __align__(16) uint16_t Ks[2 * 64 * 64];
  __shared__ __align__(16) uint16_t Vs[2 * 64 * 64];
  const int tid = threadIdx.x;
  const int wave = tid >> 6, lane = tid & 63;
  const int lrow = lane & 31;  // key_local (QK-A) / query (QK-B) / d_local (PV-B)
  const int hi = lane >> 5;

  const int bid = blockIdx.x;
  const int xcd = bid & 7;
  const int l0 = bid >> 3;
  const int bh = xcd * 8 + (l0 & 7);
  const int qblk = l0 >> 3;
  const int b = bh >> 4, h = bh & 15;
  const int q0w = qblk * 256 + wave * 64;

  const uint16_t* qbase = qm + (size_t)bh * N_SEQ * DH;
  const uint16_t* kbase = km + (size_t)bh * N_SEQ * DH;
  const uint16_t* vbase = vtm + (size_t)bh * DH * N_SEQ;

  // Q as 32x32x16 B-fragments: n = query = lrow, k(d) = step*16 + hi*8 + j
  bf16x8 qf[2][4];
#pragma unroll
  for (int qs = 0; qs < 2; ++qs) {
    const uint16_t* qp = qbase + (size_t)(q0w + qs * 32 + lrow) * DH + hi * 8;
#pragma unroll
    for (int step = 0; step < 4; ++step) qf[qs][step] = *(const bf16x8*)(qp + step * 16);
  }

  // loop-invariant swizzled LDS element offsets
  int koff[2][4];  // [ks][step]: K A-frag, row = ks*32+lrow, d = step*16+hi*8
  int voff[2][2][2];  // [ks][s][dt]: V B-frag, row(d) = dt*32+lrow, key = ks*32+s*16+hi*8
#pragma unroll
  for (int ks = 0; ks < 2; ++ks) {
    const int krow = ks * 32 + lrow;
#pragma unroll
    for (int step = 0; step < 4; ++step)
      koff[ks][step] = krow * 64 + ((((step << 1) | hi) ^ (krow & 7)) << 3);
#pragma unroll
    for (int s = 0; s < 2; ++s)
#pragma unroll
      for (int dt = 0; dt < 2; ++dt)
        voff[ks][s][dt] =
            (dt * 32 + lrow) * 64 + ((((ks << 2) | (s << 1) | hi) ^ (lrow & 7)) << 3);
  }

  f32x16 oacc[2][2];  // [qs][dt]: col = d_local = lrow, row(query) = (r&3)+8(r>>2)+4hi
#pragma unroll
  for (int qs = 0; qs < 2; ++qs)
#pragma unroll
    for (int dt = 0; dt < 2; ++dt)
#pragma unroll
      for (int i = 0; i < 16; ++i) oacc[qs][dt][i] = 0.f;
  float l[2] = {0.f, 0.f};

  // staging: 256 threads, 2 chunks each per tensor (row = key for K, d for V^T)
  const int ch = tid & 7;
  const int krow0 = tid >> 3, krow1 = 32 + (tid >> 3);
  const int kdst0 = krow0 * 64 + ((ch ^ (krow0 & 7)) << 3);
  const int kdst1 = krow1 * 64 + ((ch ^ (krow1 & 7)) << 3);

  uint4 kp0, kp1, vp0, vp1;
  kp0 = *(const uint4*)&kbase[(size_t)tid * 8];
  kp1 = *(const uint4*)&kbase[(size_t)(256 + tid) * 8];
  vp0 = *(const uint4*)&vbase[(size_t)krow0 * N_SEQ + ch * 8];
  vp1 = *(const uint4*)&vbase[(size_t)krow1 * N_SEQ + ch * 8];
  *(uint4*)&Ks[kdst0] = kp0;
  *(uint4*)&Ks[kdst1] = kp1;
  *(uint4*)&Vs[kdst0] = vp0;
  *(uint4*)&Vs[kdst1] = vp1;
  __syncthreads();

  for (int t = 0; t < N_SEQ / 64; ++t) {
    const int cur = t & 1;
    if (t < N_SEQ / 64 - 1) {
      const size_t ko = (size_t)(t + 1) * 4096;
      const int vc = (t + 1) * 64;
      kp0 = *(const uint4*)&kbase[ko + (size_t)tid * 8];
      kp1 = *(const uint4*)&kbase[ko + (size_t)(256 + tid) * 8];
      vp0 = *(const uint4*)&vbase[(size_t)krow0 * N_SEQ + vc + ch * 8];
      vp1 = *(const uint4*)&vbase[(size_t)krow1 * N_SEQ + vc + ch * 8];
    }
    const uint16_t* ksp = &Ks[cur * 4096];
    const uint16_t* vsp = &Vs[cur * 4096];

#pragma unroll
    for (int ks = 0; ks < 2; ++ks) {
      bf16x8 kf[4];
#pragma unroll
      for (int step = 0; step < 4; ++step) kf[step] = *(const bf16x8*)&ksp[koff[ks][step]];

      f32x16 z[2];
#pragma unroll
      for (int qs = 0; qs < 2; ++qs)
#pragma unroll
        for (int i = 0; i < 16; ++i) z[qs][i] = 0.f;

      __builtin_amdgcn_s_setprio(1);
#pragma unroll
      for (int step = 0; step < 4; ++step)
        z[0] = __builtin_amdgcn_mfma_f32_32x32x16_bf16(kf[step], qf[0][step], z[0], 0, 0, 0);
#pragma unroll
      for (int step = 0; step < 4; ++step)
        z[1] = __builtin_amdgcn_mfma_f32_32x32x16_bf16(kf[step], qf[1][step], z[1], 0, 0, 0);
      __builtin_amdgcn_s_setprio(0);

      // softmax piece + pack into PV A-fragments (keys hi*8+j per lane)
      uint32_t pa[2][2][4];  // [qs][s][word]
#pragma unroll
      for (int qs = 0; qs < 2; ++qs) {
        float p[16];
#pragma unroll
        for (int r = 0; r < 16; ++r) p[r] = __builtin_amdgcn_exp2f(z[qs][r]);
        l[qs] += (((p[0] + p[1]) + (p[2] + p[3])) + ((p[4] + p[5]) + (p[6] + p[7]))) +
                 (((p[8] + p[9]) + (p[10] + p[11])) + ((p[12] + p[13]) + (p[14] + p[15])));
#pragma unroll
        for (int s = 0; s < 2; ++s) {
          uint32_t w0 = pkbf(p[s * 8 + 0], p[s * 8 + 1]);
          uint32_t w1 = pkbf(p[s * 8 + 2], p[s * 8 + 3]);
          uint32_t w2 = pkbf(p[s * 8 + 4], p[s * 8 + 5]);
          uint32_t w3 = pkbf(p[s * 8 + 6], p[s * 8 + 7]);
          pswap(w0, w2);  // -> frag words 0 and 2
          pswap(w1, w3);  // -> frag words 1 and 3
          pa[qs][s][0] = w0; pa[qs][s][1] = w1; pa[qs][s][2] = w2; pa[qs][s][3] = w3;
        }
      }

      bf16x8 vf[2][2];
#pragma unroll
      for (int s = 0; s < 2; ++s)
#pragma unroll
        for (int dt = 0; dt < 2; ++dt) vf[s][dt] = *(const bf16x8*)&vsp[voff[ks][s][dt]];

      __builtin_amdgcn_s_setprio(1);
#pragma unroll
      for (int s = 0; s < 2; ++s)
#pragma unroll
        for (int qs = 0; qs < 2; ++qs) {
          uint4 u;
          u.x = pa[qs][s][0]; u.y = pa[qs][s][1]; u.z = pa[qs][s][2]; u.w = pa[qs][s][3];
          const bf16x8 paf = __builtin_bit_cast(bf16x8, u);
          oacc[qs][0] = __builtin_amdgcn_mfma_f32_32x32x16_bf16(paf, vf[s][0], oacc[qs][0], 0, 0, 0);
          oacc[qs][1] = __builtin_amdgcn_mfma_f32_32x32x16_bf16(paf, vf[s][1], oacc[qs][1], 0, 0, 0);
        }
      __builtin_amdgcn_s_setprio(0);
    }

    if (t < N_SEQ / 64 - 1) {
      // write NEXT tile into the other buffer; its previous readers finished
      // before the barrier at the end of iteration t-1.
      *(uint4*)&Ks[(cur ^ 1) * 4096 + kdst0] = kp0;
      *(uint4*)&Ks[(cur ^ 1) * 4096 + kdst1] = kp1;
      *(uint4*)&Vs[(cur ^ 1) * 4096 + kdst0] = vp0;
      *(uint4*)&Vs[(cur ^ 1) * 4096 + kdst1] = vp1;
      __syncthreads();
    }
  }

  // finalize denominators: lane's l is partial over its hi-half's key set
#pragma unroll
  for (int qs = 0; qs < 2; ++qs) l[qs] += __shfl_xor(l[qs], 32);

#pragma unroll
  for (int qs = 0; qs < 2; ++qs) {
#pragma unroll
    for (int r = 0; r < 16; ++r) {
      const int ql = (r & 3) + 8 * (r >> 2) + 4 * hi;  // query_local of this reg
      const float lr = __shfl(l[qs], ql);
      const float inv = 1.f / lr;
      const int row = q0w + qs * 32 + ql;
      const size_t base = ((size_t)b * N_SEQ + row) * 1024 + h * 64;
      om[base + lrow] = f2bf(oacc[qs][0][r] * inv);
      om[base + 32 + lrow] = f2bf(oacc[qs][1][r] * inv);
    }
  }
}

// ---------------- LayerNorm + residual ----------------
__global__ __launch_bounds__(256) void ln_res_k(const float* __restrict__ proj,
                                                const float* __restrict__ query,
                                                const float* __restrict__ gamma,
                                                const float* __restrict__ beta,
                                                float* __restrict__ out) {
  const int row = blockIdx.x;
  const int tid = threadIdx.x;
  const size_t base = (size_t)row * 1024 + tid * 4;
  float4 v = *(const float4*)(proj + base);
  float s = v.x + v.y + v.z + v.w;
  float s2 = v.x * v.x + v.y * v.y + v.z * v.z + v.w * v.w;
#pragma unroll
  for (int off = 1; off < 64; off <<= 1) {
    s += __shfl_xor(s, off);
    s2 += __shfl_xor(s2, off);
  }
  __shared__ float red[8];
  const int wave = tid >> 6, lane = tid & 63;
  if (lane == 0) { red[wave] = s; red[4 + wave] = s2; }
  __syncthreads();
  s = red[0] + red[1] + red[2] + red[3];
  s2 = red[4] + red[5] + red[6] + red[7];
  const float mu = s * (1.f / 1024.f);
  const float var = fmaxf(s2 * (1.f / 1024.f) - mu * mu, 0.f);
  const float rstd = rsqrtf(var + 1e-5f);
  float4 gq = *(const float4*)(gamma + tid * 4);
  float4 bq = *(const float4*)(beta + tid * 4);
  float4 qq = *(const float4*)(query + base);
  float4 o;
  o.x = (v.x - mu) * rstd * gq.x + bq.x + qq.x;
  o.y = (v.y - mu) * rstd * gq.y + bq.y + qq.y;
  o.z = (v.z - mu) * rstd * gq.z + bq.z + qq.z;
  o.w = (v.w - mu) * rstd * gq.w + bq.w + qq.w;
  *(float4*)(out + base) = o;
}

extern "C" void kernel_launch(void* const* d_in, const int* in_sizes, int n_in,
                              void* d_out, int out_size, void* d_ws, size_t ws_size,
                              hipStream_t stream) {
  (void)in_sizes; (void)n_in; (void)out_size; (void)ws_size;
  const float* query = (const float*)d_in[0];
  const float* key_ = (const float*)d_in[1];
  const float* value = (const float*)d_in[2];
  const float* Wq = (const float*)d_in[3];
  const float* Wk = (const float*)d_in[4];
  const float* Wv = (const float*)d_in[5];
  const float* Wo = (const float*)d_in[6];
  const float* bo = (const float*)d_in[7];
  const float* gamma = (const float*)d_in[8];
  const float* beta = (const float*)d_in[9];
  float* out = (float*)d_out;

  const size_t NELEM = (size_t)M_TOT * 1024;  // 8388608
  uint16_t* wsp = (uint16_t*)d_ws;
  uint16_t* WqT = wsp;                   // 4 x 1M bf16 (Wq,Wk,Wv,Wo contiguous)
  uint16_t* WoT = WqT + 3 * 1024 * 1024;
  uint16_t* xq = WqT + 4 * 1024 * 1024;  // xq,xk,xv contiguous (3 x NELEM)
  uint16_t* qb = xq + 3 * NELEM;         // qb,kb,vt contiguous (z * NELEM)
  uint16_t* attnO = xq;                  // alias: xq dead after QKV-GEMM
  float* proj = (float*)(xq + NELEM);    // alias: xk+xv dead after QKV-GEMM (32MB)

  // fused preprocessing: 24576 conv blocks + 4096 transpose blocks
  prep_k<<<28672, 256, 0, stream>>>(query, key_, value, Wq, Wk, Wv, Wo, xq, WqT);

  gemm_bf16<3><<<768, 512, 0, stream>>>(xq, WqT, qb, nullptr);

  attention_k<<<512, 256, 0, stream>>>(qb, qb + NELEM, qb + 2 * NELEM, attnO);

  gemm_bf16<1><<<256, 512, 0, stream>>>(attnO, WoT, proj, bo);

  ln_res_k<<<8192, 256, 0, stream>>>(proj, query, gamma, beta, out);
}